// Round 12
// baseline (1865.040 us; speedup 1.0000x reference)
//
#include <hip/hip_runtime.h>

typedef __attribute__((ext_vector_type(4))) float f32x4;
typedef __attribute__((ext_vector_type(8))) _Float16 f16x8;
typedef __attribute__((ext_vector_type(4))) _Float16 f16x4;
typedef unsigned short u16;
typedef unsigned int u32;
typedef unsigned long long u64;

#define XGCAP 34304           // rows with stored xg (non-reset ~32832, 12-sigma margin)
#define NXG 4096              // phase-1 tiles: 512 tm (128 rows) x 8 jb (192 cols)

__device__ __forceinline__ float sigm(float v){ return 1.0f / (1.0f + __expf(-v)); }
__device__ __forceinline__ float tanh_fast(float v){
  v = fminf(15.0f, fmaxf(-15.0f, v));
  float e = __expf(2.0f * v);
  return (e - 1.0f) / (e + 1.0f);
}
__device__ __forceinline__ void gload16(const void* g, void* l){
  __builtin_amdgcn_global_load_lds((const __attribute__((address_space(1))) void*)g,
                                   (__attribute__((address_space(3))) void*)l, 16, 0, 0);
}
// agent-scope atomics: coherent at L3, no cache-invalidating fences
__device__ __forceinline__ double aload(const double* p){
  return __hip_atomic_load(p, __ATOMIC_RELAXED, __HIP_MEMORY_SCOPE_AGENT);
}
__device__ __forceinline__ void astore(float* p, float v){
  __hip_atomic_store(p, v, __ATOMIC_RELAXED, __HIP_MEMORY_SCOPE_AGENT);
}
__device__ __forceinline__ u32 apoll(const u32* p){
  return __hip_atomic_load(p, __ATOMIC_RELAXED, __HIP_MEMORY_SCOPE_AGENT);
}
__device__ __forceinline__ void abump(u32* p, u32 v){
  __hip_atomic_fetch_add(p, v, __ATOMIC_RELAXED, __HIP_MEMORY_SCOPE_AGENT);
}
__device__ __forceinline__ float2 d2f2(double d){ union{double d; float2 f;} u; u.d = d; return u.f; }

// ---------------------------------------------------------------------------
// P1 v4: FULLY PARALLEL depth-list builder. depth(t,b) = t - lastSetBit<=t of
// (reset-column | bit0) -> per-cell independent (no serial chains). 512 thr:
// thread (b = tid&127, tc = tid>>7) owns 128 cells. Per-thread level counts
// for li<8 packed in a u64 (8x8-bit, static extraction -> registers, no
// scratch); li>=8 rare -> LDS atomics. Deterministic placement.
// rows[] entry: t | b<<9 | fl<<16 (0=wait, 1=xg-handled, 2=h0).
// ---------------------------------------------------------------------------
__global__ __launch_bounds__(512) void prep_lists(
    const void* __restrict__ resets_raw, const float* __restrict__ h0,
    u32* __restrict__ rows, u32* __restrict__ off, int* __restrict__ nlists)
{
  __shared__ u64 cb[128][8];       // column bits: cb[b][w], bit (t&63) of word t>>6
  __shared__ u32 cnt8[8][512];     // per-level<8 per-thread counts -> excl. prefix
  __shared__ u32 cnt[520];
  __shared__ u32 offs[521];
  __shared__ u32 cur[520];
  __shared__ int is_bytes, h0nz, maxli;
  const int tid = threadIdx.x;
  const int b = tid & 127, tc = tid >> 7;
  for (int i = tid; i < 520; i += 512){ cnt[i] = 0; cur[i] = 0; }
  if (tid == 0){ is_bytes = 0; h0nz = 0; maxli = 0; }
  for (int i = tid; i < 64; i += 512) rows[65536 + i] = (2u << 16); // pad: no wait
  __syncthreads();
  { // resets dtype sniff: int32 -> all words 0/1; packed bytes -> words >1 whp
    const u32* w = (const u32*)resets_raw;
    int bad = 0;
    for (int i = tid; i < 4096; i += 512) bad |= (w[i] > 1u);
    if (bad) atomicOr(&is_bytes, 1);
  }
  { // h0 == 0 sniff
    const u32* hw = (const u32*)h0;
    u32 o = 0;
    for (int i = tid; i < 65536; i += 512) o |= hw[i];
    if (o) atomicOr(&h0nz, 1);
  }
  __syncthreads();
  const bool h0zero = (h0nz == 0);
  // build column bits (coalesced: lanes of a tc-group read consecutive b)
  u64 bits0 = 0, bits1 = 0;
  if (is_bytes){
    const unsigned char* ru8 = (const unsigned char*)resets_raw;
    for (int i = 0; i < 128; ++i){
      int t = tc*128 + i;
      if (ru8[t*128 + b]){
        if (i < 64) bits0 |= 1ull << i; else bits1 |= 1ull << (i - 64);
      }
    }
  } else {
    const u32* ri32 = (const u32*)resets_raw;
    for (int i = 0; i < 128; ++i){
      int t = tc*128 + i;
      if (ri32[t*128 + b]){
        if (i < 64) bits0 |= 1ull << i; else bits1 |= 1ull << (i - 64);
      }
    }
  }
  cb[b][tc*2]     = bits0;
  cb[b][tc*2 + 1] = bits1;
  __syncthreads();

#define CELL_LI() \
    u64 myw = (i < 64) ? bits0 : bits1; \
    int rs = (int)((myw >> (i & 63)) & 1ull); \
    int k = t >> 6; \
    u64 m = cb[b][k] | (k == 0 ? 1ull : 0ull); \
    int r6 = t & 63; \
    m &= (r6 == 63) ? ~0ull : ((1ull << (r6 + 1)) - 1ull); \
    while (m == 0ull){ --k; m = cb[b][k] | (k == 0 ? 1ull : 0ull); } \
    int lastE = (k << 6) + 63 - (int)__builtin_clzll(m); \
    int depth = t - lastE; \
    int li = (depth == 0) ? ((rs || h0zero) ? 0 : 1) : (depth + 1);

  // pass 1: count (u64-packed register counters for li<8)
  {
    u64 cpack = 0;
    int lmax = 0;
    for (int i = 0; i < 128; ++i){
      const int t = tc*128 + i;
      CELL_LI();
      if (li > lmax) lmax = li;
      if (li < 8) cpack += 1ull << (li * 8);
      else atomicAdd(&cnt[li], 1u);
    }
    atomicMax(&maxli, lmax);
    #pragma unroll
    for (int l = 0; l < 8; ++l) cnt8[l][tid] = (u32)((cpack >> (l * 8)) & 0xFFull);
  }
  __syncthreads();
  if (tid < 8){  // exclusive prefix over 512 threads per level
    u32 s = 0;
    for (int i = 0; i < 512; ++i){ u32 v = cnt8[tid][i]; cnt8[tid][i] = s; s += v; }
    cnt[tid] = s;
  }
  __syncthreads();
  if (tid == 0){
    u32 s = 0;
    for (int i = 0; i < 520; ++i){ offs[i] = s; s += cnt[i]; }
    offs[520] = s;
    *nlists = maxli + 1;
  }
  __syncthreads();
  for (int i = tid; i < 521; i += 512) off[i] = offs[i];
  __syncthreads();
  // pass 2: deterministic placement
  {
    u64 lcpack = 0;
    for (int i = 0; i < 128; ++i){
      const int t = tc*128 + i;
      CELL_LI();
      u32 p;
      if (li < 8){
        u32 loc = (u32)((lcpack >> (li * 8)) & 0xFFull);
        lcpack += 1ull << (li * 8);
        p = offs[li] + cnt8[li][tid] + loc;
      } else {
        p = offs[li] + atomicAdd(&cur[li], 1u);
      }
      u32 fl = rs ? 1u : ((t == 0) ? (h0zero ? 1u : 2u) : 0u);
      rows[p] = (u32)t | ((u32)b << 9) | (fl << 16);
    }
  }
#undef CELL_LI
}

// ---------------------------------------------------------------------------
// P2: pre-swizzled fp16 W images wimg[jblk][kc 0..15][24576B] + zero both
// flag arrays (128 KB contiguous, blocks 0..127).
// ---------------------------------------------------------------------------
__global__ void prep_w(const float* __restrict__ Wi, const float* __restrict__ Wh,
                       char* __restrict__ wimg, u32* __restrict__ zflags)
{
  if (blockIdx.x < 128){
    #pragma unroll
    for (int i = 0; i < 4; ++i)
      zflags[blockIdx.x * 1024 + (int)threadIdx.x + i * 256] = 0;
  }
  __shared__ float tile[64][65];
  const int bc = blockIdx.x % 24;
  const int bk = blockIdx.x / 24;
  const int scol0 = (bc % 3) * 512 + (bc / 3) * 64;
  const int k0 = bk * 64;
  #pragma unroll
  for (int i = 0; i < 4; ++i){
    int idx = (int)threadIdx.x + i*256;
    int kk = idx >> 4, c4 = idx & 15;
    int k = k0 + kk;
    const float* src = (k < 512) ? (Wi + (size_t)k*1536 + scol0 + c4*4)
                                 : (Wh + (size_t)(k-512)*1536 + scol0 + c4*4);
    float4 v = *(const float4*)src;
    tile[kk][c4*4+0] = v.x; tile[kk][c4*4+1] = v.y;
    tile[kk][c4*4+2] = v.z; tile[kk][c4*4+3] = v.w;
  }
  __syncthreads();
  const int jb = bc / 3;
  #pragma unroll
  for (int i = 0; i < 4; ++i){
    int idx = (int)threadIdx.x + i*256;
    int cc = idx >> 4, k4 = idx & 15;
    int cimg = (bc % 3)*64 + cc;
    f16x4 c;
    c[0] = (_Float16)tile[k4*4+0][cc]; c[1] = (_Float16)tile[k4*4+1][cc];
    c[2] = (_Float16)tile[k4*4+2][cc]; c[3] = (_Float16)tile[k4*4+3][cc];
    int bby = k4*8;
    int sb = (bby & 8) | ((bby & 0x70) ^ ((cimg & 7) << 4));
    *(f16x4*)(wimg + ((size_t)(jb*16 + bk))*24576 + cimg*128 + sb) = c;
  }
}

// ---------------------------------------------------------------------------
// P3: gather-convert x -> xq fp16 [65536 rows][1024 B], list-ordered and
// PRE-SWIZZLED per 128-B chunk. 16 rows/block, coalesced.
// ---------------------------------------------------------------------------
__global__ __launch_bounds__(256) void prep_x(
    const float* __restrict__ x, const u32* __restrict__ rows,
    char* __restrict__ xq)
{
  const int tid = threadIdx.x;
  const u32 lpos = blockIdx.x * 16 + (tid >> 4);
  const u32 e = rows[lpos];
  const float* src = x + ((size_t)((e & 511u)*128u + ((e >> 9) & 127u)))*512;
  const int lane16 = tid & 15;
  char* dst = xq + (size_t)lpos * 1024;
  const int swzr = ((int)lpos & 7) << 4;
  #pragma unroll
  for (int it = 0; it < 8; ++it){
    float4 v = *(const float4*)(src + it*64 + lane16*4);
    f16x4 c; c[0]=(_Float16)v.x; c[1]=(_Float16)v.y;
             c[2]=(_Float16)v.z; c[3]=(_Float16)v.w;
    int bby = lane16 * 8;
    int sb = (bby & 8) | ((bby & 0x70) ^ swzr);
    *(f16x4*)(dst + it*128 + sb) = c;
  }
}

// ---------------------------------------------------------------------------
// Fused: phase 1 = DMA GEMM (128x192 tiles, A+W via global_load_lds, dbuf);
// phase 2 = scan dataflow with jb-PAIR tiles (64 rows x 128 cols): halves
// redundant h-gather + handshakes, doubles MFMA density. hflags>=8, xflags>=8.
// ---------------------------------------------------------------------------
__global__ __launch_bounds__(256, 2) void gru_fused(
    const char* __restrict__ xq, const float* __restrict__ bi,
    const float* __restrict__ bhn, const char* __restrict__ wimg,
    const float* __restrict__ h0, _Float16* __restrict__ xg,
    const u32* __restrict__ rows, const u32* __restrict__ off,
    const int* __restrict__ nlists, u32* __restrict__ hflags,
    u32* __restrict__ xflags, float* __restrict__ out)
{
  __shared__ __align__(16) char smem[81920];  // ph1: A 2x16K | W 2x24K @32768; ph2: ring 4x8K
  float* ys = out + 65536;
  const u32 n0 = off[1];
  const int tid = threadIdx.x;
  const int lane = tid & 63, wave = tid >> 6;
  const int nblk = (int)gridDim.x;

  // ================= phase 1: xg GEMM tiles (full DMA staging) =============
  int g = (int)blockIdx.x;
  while (g < NXG){
    const int tm = g >> 3, jb = g & 7;
    g += nblk;
    const char* asrc = xq + (size_t)tm * 131072;          // 128 rows x 1024 B
    const char* wsrc = wimg + ((size_t)jb * 16) * 24576;

    f32x4 acc[3][8];
    #pragma unroll
    for (int c = 0; c < 3; ++c)
      #pragma unroll
      for (int m = 0; m < 8; ++m) acc[c][m] = (f32x4){0.f,0.f,0.f,0.f};

#define DMA_A(KC, BUF) do{ \
    char* l_ = smem + (BUF)*16384 + wave*4096; \
    const char* g_ = asrc + (size_t)(wave*32 + (lane>>3))*1024 + (KC)*128 + (lane&7)*16; \
    _Pragma("unroll") for (int i_ = 0; i_ < 4; ++i_) \
      gload16(g_ + i_*8192, l_ + i_*1024); }while(0)
#define DMA_W(KC, BUF) do{ \
    char* l_ = smem + 32768 + (BUF)*24576 + wave*6144; \
    const char* g_ = wsrc + (size_t)(KC)*24576 + wave*6144 + lane*16; \
    _Pragma("unroll") for (int i_ = 0; i_ < 6; ++i_) \
      gload16(g_ + i_*1024, l_ + i_*1024); }while(0)

    DMA_A(0, 0); DMA_W(0, 0);
    __syncthreads();
    for (int kc = 0; kc < 8; ++kc){
      const int cur = kc & 1;
      if (kc < 7){ DMA_A(kc+1, cur^1); DMA_W(kc+1, cur^1); }
      const char* Ab = smem + cur*16384;
      const char* Wb = smem + 32768 + cur*24576;
      #pragma unroll
      for (int kk = 0; kk < 2; ++kk){
        const int bby = kk*64 + (lane>>4)*16;
        f16x8 af[8];
        #pragma unroll
        for (int mi = 0; mi < 8; ++mi){
          int rr = mi*16 + (lane & 15);
          af[mi] = *(const f16x8*)(Ab + rr*128 + (bby ^ ((rr & 7) << 4)));
        }
        #pragma unroll
        for (int cls = 0; cls < 3; ++cls){
          int cc = cls*64 + wave*16 + (lane & 15);
          f16x8 wf = *(const f16x8*)(Wb + cc*128 + (bby ^ ((cc & 7) << 4)));
          #pragma unroll
          for (int mi = 0; mi < 8; ++mi)
            acc[cls][mi] = __builtin_amdgcn_mfma_f32_16x16x32_f16(af[mi], wf, acc[cls][mi], 0, 0, 0);
        }
      }
      __syncthreads();
    }
#undef DMA_A
#undef DMA_W

    const int jloc = wave*16 + (lane & 15);
    const int j = jb*64 + jloc;
    const float bir = bi[j], biz = bi[512 + j], bin = bi[1024 + j], bh = bhn[j];
    #pragma unroll
    for (int mi = 0; mi < 8; ++mi){
      #pragma unroll
      for (int rg = 0; rg < 4; ++rg){
        int r = mi*16 + (lane >> 4)*4 + rg;
        u32 e = rows[tm*128 + r];
        int tt = (int)(e & 511u), bb = (int)((e >> 9) & 127u);
        float xr = acc[0][mi][rg] + bir;
        float xz = acc[1][mi][rg] + biz;
        float xn = acc[2][mi][rg] + bin;
        if ((e >> 16) == 1u){        // reset/fold row: h = (1-z)*n
          float rr = sigm(xr), zz = sigm(xz);
          float nn = tanh_fast(xn + rr*bh);
          float hv = (1.f - zz)*nn;
          ys[((size_t)(tt*128 + bb))*512 + j] = hv;
          if (tt == 511) out[(size_t)bb*512 + j] = hv;
        } else {
          u32 xi = (u32)(tm*128 + r) - n0;
          if (xi >= XGCAP) xi = 0;
          _Float16* p = xg + (size_t)xi*1536 + jb*192 + jloc;
          p[0]   = (_Float16)xr;
          p[64]  = (_Float16)xz;
          p[128] = (_Float16)xn;
        }
      }
    }
    __syncthreads();   // all stores drained before flag bumps
    if (tid < 128){
      u32 e = rows[tm*128 + tid];
      if ((e >> 16) == 1u) abump(&hflags[(e & 511u)*128u + ((e >> 9) & 127u)], 1u);
      else                 abump(&xflags[tm*128 + tid], 1u);
    }
    __syncthreads();
  }

  // ============ phase 2: scan tiles (jb-pair, 64 rows x 128 cols) ==========
  const int L = *nlists;
  int myNext = g - NXG;
  int gt = 0;
  for (int li = 1; li < L; ++li){
    const u32 offA = off[li];
    const int nA = (int)(off[li+1] - offA);
    const int tA = (nA + 63) >> 6;
    const int nt = tA * 4;
    while (myNext < gt + nt){
      const int tile = myNext - gt;
      myNext += nblk;
      const int tm = tile >> 2, jp = tile & 3;
      const int jb0 = jp*2, jb1 = jp*2 + 1;
      const u32 rowbase = offA + (u32)tm*64u;
      const u32 xibase = rowbase - n0;
      const int mcount = min(64, nA - tm*64);
      const char* wp0 = wimg + ((size_t)jb0*16 + 8)*24576;
      const char* wp1 = wimg + ((size_t)jb1*16 + 8)*24576;
      const int jloc = wave*16 + (lane & 15);

      // wait: wave 0 polls xg readiness (own rows) + h readiness (preds)
      if (wave == 0 && lane < mcount){
        u32 e = rows[rowbase + lane];
        const bool needH = ((e >> 16) == 0u);
        u32 hidx = ((e & 511u) - 1u)*128u + ((e >> 9) & 127u);
        int guard = 0;
        for (;;){
          bool ok = apoll(&xflags[rowbase + lane]) >= 8u;
          if (ok && needH) ok = apoll(&hflags[hidx]) >= 8u;
          if (ok) break;
          __builtin_amdgcn_s_sleep(1);
          if (++guard > (1 << 20)) break;
        }
      }
      __syncthreads();

      const float* rp[4];
      #pragma unroll
      for (int i = 0; i < 4; ++i){
        u32 e = rows[rowbase + (tid>>4) + i*16];
        int tt = (int)(e & 511u), bb = (int)((e >> 9) & 127u);
        const float* base = ((e >> 16) == 0u) ? (ys + ((size_t)((tt-1)*128 + bb))*512)
                                              : (h0 + (size_t)bb*512);
        rp[i] = base + (tid & 15)*4;
      }

      // xg prefetch: 96 halves/thread, in flight across the K-pipeline
      _Float16 xgp[2][3][4][4];
      #pragma unroll
      for (int q = 0; q < 2; ++q){
        #pragma unroll
        for (int mi = 0; mi < 4; ++mi){
          #pragma unroll
          for (int rg = 0; rg < 4; ++rg){
            u32 xi = xibase + (u32)(mi*16 + (lane >> 4)*4 + rg);
            if (xi >= XGCAP) xi = 0;
            const _Float16* p = xg + (size_t)xi*1536 + (jp*2 + q)*192 + jloc;
            xgp[q][0][mi][rg] = p[0];
            xgp[q][1][mi][rg] = p[64];
            xgp[q][2][mi][rg] = p[128];
          }
        }
      }

      f32x4 acc[2][3][4];
      #pragma unroll
      for (int q = 0; q < 2; ++q)
        #pragma unroll
        for (int c = 0; c < 3; ++c)
          #pragma unroll
          for (int m = 0; m < 4; ++m) acc[q][c][m] = (f32x4){0.f,0.f,0.f,0.f};
      _Float16 hp[2][4][4];
      double s0[4][2], s1[4][2], s2[4][2];

#define ALOAD(S, CK) do{ \
    _Pragma("unroll") for (int i_ = 0; i_ < 4; ++i_){ \
      const double* p_ = (const double*)(rp[i_] + (CK)*64); \
      S[i_][0] = aload(p_); S[i_][1] = aload(p_ + 1); } }while(0)

#define AWRITE(S, CK) do{ \
    char* An_ = smem + ((CK) & 3)*8192; \
    _Pragma("unroll") for (int i_ = 0; i_ < 4; ++i_){ \
      float2 u0_ = d2f2(S[i_][0]), u1_ = d2f2(S[i_][1]); \
      int r_ = (tid>>4) + i_*16, bby_ = (tid & 15)*8; \
      int sb_ = (bby_ & 8) | ((bby_ & 0x70) ^ ((r_ & 7) << 4)); \
      f16x4 c_; c_[0]=(_Float16)u0_.x; c_[1]=(_Float16)u0_.y; \
                c_[2]=(_Float16)u1_.x; c_[3]=(_Float16)u1_.y; \
      *(f16x4*)(An_ + r_*128 + sb_) = c_; } }while(0)

#define CAPTURE_HP(Q, KC) { \
      const char* Ab2_ = smem + ((KC) & 3)*8192; \
      const int bb2_ = jloc*2; \
      _Pragma("unroll") for (int mi_ = 0; mi_ < 4; ++mi_) \
        _Pragma("unroll") for (int rg_ = 0; rg_ < 4; ++rg_){ \
          int r2_ = mi_*16 + (lane >> 4)*4 + rg_; \
          int sb2_ = (bb2_ & 0x0F) | ((bb2_ & 0x70) ^ ((r2_ & 7) << 4)); \
          hp[Q][mi_][rg_] = *(const _Float16*)(Ab2_ + r2_*128 + sb2_); } }

#define COMPUTE(KC) do{ \
    const char* Ab_ = smem + ((KC) & 3)*8192; \
    _Pragma("unroll") for (int kk_ = 0; kk_ < 2; ++kk_){ \
      const int bby_ = kk_*64 + (lane>>4)*16; \
      f16x8 af_[4]; \
      _Pragma("unroll") for (int mi_ = 0; mi_ < 4; ++mi_){ \
        int rr_ = mi_*16 + (lane & 15); \
        af_[mi_] = *(const f16x8*)(Ab_ + rr_*128 + (bby_ ^ ((rr_ & 7) << 4))); } \
      _Pragma("unroll") for (int q_ = 0; q_ < 2; ++q_){ \
        const char* wpq_ = (q_ == 0) ? wp0 : wp1; \
        _Pragma("unroll") for (int cl_ = 0; cl_ < 3; ++cl_){ \
          int cc_ = cl_*64 + wave*16 + (lane & 15); \
          f16x8 wf_ = *(const f16x8*)(wpq_ + (size_t)(KC)*24576 + cc_*128 + (bby_ ^ ((cc_ & 7) << 4))); \
          _Pragma("unroll") for (int mi_ = 0; mi_ < 4; ++mi_) \
            acc[q_][cl_][mi_] = __builtin_amdgcn_mfma_f32_16x16x32_f16(af_[mi_], wf_, acc[q_][cl_][mi_], 0, 0, 0); } } } \
    if ((KC) == jb0) CAPTURE_HP(0, KC) \
    if ((KC) == jb1) CAPTURE_HP(1, KC) }while(0)

      ALOAD(s0, 0); ALOAD(s1, 1); ALOAD(s2, 2);
      AWRITE(s0, 0);
      __syncthreads();
      ALOAD(s0, 3); COMPUTE(0); AWRITE(s1, 1); __syncthreads();
      ALOAD(s1, 4); COMPUTE(1); AWRITE(s2, 2); __syncthreads();
      ALOAD(s2, 5); COMPUTE(2); AWRITE(s0, 3); __syncthreads();
      ALOAD(s0, 6); COMPUTE(3); AWRITE(s1, 4); __syncthreads();
      ALOAD(s1, 7); COMPUTE(4); AWRITE(s2, 5); __syncthreads();
                    COMPUTE(5); AWRITE(s0, 6); __syncthreads();
                    COMPUTE(6); AWRITE(s1, 7); __syncthreads();
                    COMPUTE(7);
#undef ALOAD
#undef AWRITE
#undef COMPUTE
#undef CAPTURE_HP

      // epilogue: gates + h_new -> ys (agent stores) + out for t=511
      #pragma unroll
      for (int q = 0; q < 2; ++q){
        const int j = (jp*2 + q)*64 + jloc;
        const float bh = bhn[j];
        #pragma unroll
        for (int mi = 0; mi < 4; ++mi){
          #pragma unroll
          for (int rg = 0; rg < 4; ++rg){
            int r = mi*16 + (lane >> 4)*4 + rg;
            if (r < mcount){
              u32 e = rows[rowbase + r];
              int tt = (int)(e & 511u), bb = (int)((e >> 9) & 127u);
              float rr = sigm((float)xgp[q][0][mi][rg] + acc[q][0][mi][rg]);
              float zz = sigm((float)xgp[q][1][mi][rg] + acc[q][1][mi][rg]);
              float nn = tanh_fast((float)xgp[q][2][mi][rg] + rr*(acc[q][2][mi][rg] + bh));
              float hv = (1.f - zz)*nn + zz*(float)hp[q][mi][rg];
              astore(&ys[((size_t)(tt*128 + bb))*512 + j], hv);
              if (tt == 511) out[(size_t)bb*512 + j] = hv;
            }
          }
        }
      }
      __syncthreads();   // vmcnt(0) drained -> ys stores at coherence point
      if (tid < mcount){
        u32 e = rows[rowbase + tid];
        abump(&hflags[(e & 511u)*128u + ((e >> 9) & 127u)], 2u);
      }
    }
    gt += nt;
  }
}

// ---------------------------------------------------------------------------
extern "C" void kernel_launch(void* const* d_in, const int* in_sizes, int n_in,
                              void* d_out, int out_size, void* d_ws, size_t ws_size,
                              hipStream_t stream)
{
  const float* x  = (const float*)d_in[0];
  const void*  resets = d_in[1];
  const float* h0 = (const float*)d_in[2];
  const float* Wi = (const float*)d_in[3];
  const float* bi = (const float*)d_in[4];
  const float* Wh = (const float*)d_in[5];
  const float* bhn= (const float*)d_in[6];
  float* out = (float*)d_out;

  char* ws = (char*)d_ws;
  u32* off    = (u32*)ws;                       // 521 u32
  int* nlists = (int*)(ws + 4096);
  u32* rows   = (u32*)(ws + 8192);              // 65600 u32
  u32* hflags = (u32*)(ws + 294912);            // 65536 u32
  u32* xflags = (u32*)(ws + 557056);            // 65536 u32 (contiguous after hflags)
  char* wimg  = ws + 819200;                    // 3.07 MB
  char* xq    = ws + 4194304;                   // 67.1 MB
  _Float16* xg = (_Float16*)(ws + 71303168);    // XGCAP*1536 fp16 = 105.4 MB

  prep_lists<<<dim3(1), dim3(512), 0, stream>>>(resets, h0, rows, off, nlists);
  prep_w<<<dim3(384), dim3(256), 0, stream>>>(Wi, Wh, wimg, hflags);
  prep_x<<<dim3(4096), dim3(256), 0, stream>>>(x, rows, xq);

  int perCU = 0;
  (void)hipOccupancyMaxActiveBlocksPerMultiprocessor(&perCU, gru_fused, 256, 0);
  if (perCU < 1) perCU = 1;
  int grid = perCU * 256;
  if (grid > 1024) grid = 1024;

  void* args[] = {(void*)&xq, (void*)&bi, (void*)&bhn, (void*)&wimg,
                  (void*)&h0, (void*)&xg, (void*)&rows, (void*)&off,
                  (void*)&nlists, (void*)&hflags, (void*)&xflags, (void*)&out};
  hipLaunchCooperativeKernel(gru_fused, dim3(grid), dim3(256), args, 0, stream);

  (void)in_sizes; (void)n_in; (void)out_size; (void)ws_size;
}

// Round 13
// 931.170 us; speedup vs baseline: 2.0029x; 2.0029x over previous
//
#include <hip/hip_runtime.h>

typedef __attribute__((ext_vector_type(4))) float f32x4;
typedef __attribute__((ext_vector_type(8))) _Float16 f16x8;
typedef __attribute__((ext_vector_type(4))) _Float16 f16x4;
typedef unsigned short u16;
typedef unsigned int u32;
typedef unsigned long long u64;

#define XGCAP 34304           // rows with stored xg (non-reset ~32832, 12-sigma margin)
#define NXG 4096              // phase-1 tiles: 512 tm (128 rows) x 8 jb (192 cols)

__device__ __forceinline__ float sigm(float v){ return 1.0f / (1.0f + __expf(-v)); }
__device__ __forceinline__ float tanh_fast(float v){
  v = fminf(15.0f, fmaxf(-15.0f, v));
  float e = __expf(2.0f * v);
  return (e - 1.0f) / (e + 1.0f);
}
__device__ __forceinline__ void gload16(const void* g, void* l){
  __builtin_amdgcn_global_load_lds((const __attribute__((address_space(1))) void*)g,
                                   (__attribute__((address_space(3))) void*)l, 16, 0, 0);
}
// agent-scope atomics: coherent at L3, no cache-invalidating fences
__device__ __forceinline__ double aload(const double* p){
  return __hip_atomic_load(p, __ATOMIC_RELAXED, __HIP_MEMORY_SCOPE_AGENT);
}
__device__ __forceinline__ void astore(float* p, float v){
  __hip_atomic_store(p, v, __ATOMIC_RELAXED, __HIP_MEMORY_SCOPE_AGENT);
}
__device__ __forceinline__ u32 apoll(const u32* p){
  return __hip_atomic_load(p, __ATOMIC_RELAXED, __HIP_MEMORY_SCOPE_AGENT);
}
__device__ __forceinline__ void abump(u32* p, u32 v){
  __hip_atomic_fetch_add(p, v, __ATOMIC_RELAXED, __HIP_MEMORY_SCOPE_AGENT);
}
__device__ __forceinline__ float2 d2f2(double d){ union{double d; float2 f;} u; u.d = d; return u.f; }

// ---------------------------------------------------------------------------
// P1 v4 (proven in R12): FULLY PARALLEL depth-list builder. depth(t,b) =
// t - lastSetBit<=t of (reset-column | bit0) -> per-cell independent. 512 thr:
// thread (b = tid&127, tc = tid>>7) owns 128 cells. Per-thread level counts
// for li<8 packed in a u64 (static extraction -> registers); li>=8 rare ->
// LDS atomics. Deterministic placement.
// rows[] entry: t | b<<9 | fl<<16 (0=wait, 1=xg-handled, 2=h0).
// ---------------------------------------------------------------------------
__global__ __launch_bounds__(512) void prep_lists(
    const void* __restrict__ resets_raw, const float* __restrict__ h0,
    u32* __restrict__ rows, u32* __restrict__ off, int* __restrict__ nlists)
{
  __shared__ u64 cb[128][8];
  __shared__ u32 cnt8[8][512];
  __shared__ u32 cnt[520];
  __shared__ u32 offs[521];
  __shared__ u32 cur[520];
  __shared__ int is_bytes, h0nz, maxli;
  const int tid = threadIdx.x;
  const int b = tid & 127, tc = tid >> 7;
  for (int i = tid; i < 520; i += 512){ cnt[i] = 0; cur[i] = 0; }
  if (tid == 0){ is_bytes = 0; h0nz = 0; maxli = 0; }
  for (int i = tid; i < 64; i += 512) rows[65536 + i] = (2u << 16); // pad: no wait
  __syncthreads();
  { // resets dtype sniff
    const u32* w = (const u32*)resets_raw;
    int bad = 0;
    for (int i = tid; i < 4096; i += 512) bad |= (w[i] > 1u);
    if (bad) atomicOr(&is_bytes, 1);
  }
  { // h0 == 0 sniff
    const u32* hw = (const u32*)h0;
    u32 o = 0;
    for (int i = tid; i < 65536; i += 512) o |= hw[i];
    if (o) atomicOr(&h0nz, 1);
  }
  __syncthreads();
  const bool h0zero = (h0nz == 0);
  u64 bits0 = 0, bits1 = 0;
  if (is_bytes){
    const unsigned char* ru8 = (const unsigned char*)resets_raw;
    for (int i = 0; i < 128; ++i){
      int t = tc*128 + i;
      if (ru8[t*128 + b]){
        if (i < 64) bits0 |= 1ull << i; else bits1 |= 1ull << (i - 64);
      }
    }
  } else {
    const u32* ri32 = (const u32*)resets_raw;
    for (int i = 0; i < 128; ++i){
      int t = tc*128 + i;
      if (ri32[t*128 + b]){
        if (i < 64) bits0 |= 1ull << i; else bits1 |= 1ull << (i - 64);
      }
    }
  }
  cb[b][tc*2]     = bits0;
  cb[b][tc*2 + 1] = bits1;
  __syncthreads();

#define CELL_LI() \
    u64 myw = (i < 64) ? bits0 : bits1; \
    int rs = (int)((myw >> (i & 63)) & 1ull); \
    int k = t >> 6; \
    u64 m = cb[b][k] | (k == 0 ? 1ull : 0ull); \
    int r6 = t & 63; \
    m &= (r6 == 63) ? ~0ull : ((1ull << (r6 + 1)) - 1ull); \
    while (m == 0ull){ --k; m = cb[b][k] | (k == 0 ? 1ull : 0ull); } \
    int lastE = (k << 6) + 63 - (int)__builtin_clzll(m); \
    int depth = t - lastE; \
    int li = (depth == 0) ? ((rs || h0zero) ? 0 : 1) : (depth + 1);

  {
    u64 cpack = 0;
    int lmax = 0;
    for (int i = 0; i < 128; ++i){
      const int t = tc*128 + i;
      CELL_LI();
      if (li > lmax) lmax = li;
      if (li < 8) cpack += 1ull << (li * 8);
      else atomicAdd(&cnt[li], 1u);
    }
    atomicMax(&maxli, lmax);
    #pragma unroll
    for (int l = 0; l < 8; ++l) cnt8[l][tid] = (u32)((cpack >> (l * 8)) & 0xFFull);
  }
  __syncthreads();
  if (tid < 8){
    u32 s = 0;
    for (int i = 0; i < 512; ++i){ u32 v = cnt8[tid][i]; cnt8[tid][i] = s; s += v; }
    cnt[tid] = s;
  }
  __syncthreads();
  if (tid == 0){
    u32 s = 0;
    for (int i = 0; i < 520; ++i){ offs[i] = s; s += cnt[i]; }
    offs[520] = s;
    *nlists = maxli + 1;
  }
  __syncthreads();
  for (int i = tid; i < 521; i += 512) off[i] = offs[i];
  __syncthreads();
  {
    u64 lcpack = 0;
    for (int i = 0; i < 128; ++i){
      const int t = tc*128 + i;
      CELL_LI();
      u32 p;
      if (li < 8){
        u32 loc = (u32)((lcpack >> (li * 8)) & 0xFFull);
        lcpack += 1ull << (li * 8);
        p = offs[li] + cnt8[li][tid] + loc;
      } else {
        p = offs[li] + atomicAdd(&cur[li], 1u);
      }
      u32 fl = rs ? 1u : ((t == 0) ? (h0zero ? 1u : 2u) : 0u);
      rows[p] = (u32)t | ((u32)b << 9) | (fl << 16);
    }
  }
#undef CELL_LI
}

// ---------------------------------------------------------------------------
// P2: pre-swizzled fp16 W images wimg[jblk][kc 0..15][24576B] + zero both
// flag arrays (128 KB contiguous, blocks 0..127).
// ---------------------------------------------------------------------------
__global__ void prep_w(const float* __restrict__ Wi, const float* __restrict__ Wh,
                       char* __restrict__ wimg, u32* __restrict__ zflags)
{
  if (blockIdx.x < 128){
    #pragma unroll
    for (int i = 0; i < 4; ++i)
      zflags[blockIdx.x * 1024 + (int)threadIdx.x + i * 256] = 0;
  }
  __shared__ float tile[64][65];
  const int bc = blockIdx.x % 24;
  const int bk = blockIdx.x / 24;
  const int scol0 = (bc % 3) * 512 + (bc / 3) * 64;
  const int k0 = bk * 64;
  #pragma unroll
  for (int i = 0; i < 4; ++i){
    int idx = (int)threadIdx.x + i*256;
    int kk = idx >> 4, c4 = idx & 15;
    int k = k0 + kk;
    const float* src = (k < 512) ? (Wi + (size_t)k*1536 + scol0 + c4*4)
                                 : (Wh + (size_t)(k-512)*1536 + scol0 + c4*4);
    float4 v = *(const float4*)src;
    tile[kk][c4*4+0] = v.x; tile[kk][c4*4+1] = v.y;
    tile[kk][c4*4+2] = v.z; tile[kk][c4*4+3] = v.w;
  }
  __syncthreads();
  const int jb = bc / 3;
  #pragma unroll
  for (int i = 0; i < 4; ++i){
    int idx = (int)threadIdx.x + i*256;
    int cc = idx >> 4, k4 = idx & 15;
    int cimg = (bc % 3)*64 + cc;
    f16x4 c;
    c[0] = (_Float16)tile[k4*4+0][cc]; c[1] = (_Float16)tile[k4*4+1][cc];
    c[2] = (_Float16)tile[k4*4+2][cc]; c[3] = (_Float16)tile[k4*4+3][cc];
    int bby = k4*8;
    int sb = (bby & 8) | ((bby & 0x70) ^ ((cimg & 7) << 4));
    *(f16x4*)(wimg + ((size_t)(jb*16 + bk))*24576 + cimg*128 + sb) = c;
  }
}

// ---------------------------------------------------------------------------
// P3: gather-convert x -> xq fp16 [65536 rows][1024 B], list-ordered and
// PRE-SWIZZLED per 128-B chunk. 16 rows/block, coalesced.
// ---------------------------------------------------------------------------
__global__ __launch_bounds__(256) void prep_x(
    const float* __restrict__ x, const u32* __restrict__ rows,
    char* __restrict__ xq)
{
  const int tid = threadIdx.x;
  const u32 lpos = blockIdx.x * 16 + (tid >> 4);
  const u32 e = rows[lpos];
  const float* src = x + ((size_t)((e & 511u)*128u + ((e >> 9) & 127u)))*512;
  const int lane16 = tid & 15;
  char* dst = xq + (size_t)lpos * 1024;
  const int swzr = ((int)lpos & 7) << 4;
  #pragma unroll
  for (int it = 0; it < 8; ++it){
    float4 v = *(const float4*)(src + it*64 + lane16*4);
    f16x4 c; c[0]=(_Float16)v.x; c[1]=(_Float16)v.y;
             c[2]=(_Float16)v.z; c[3]=(_Float16)v.w;
    int bby = lane16 * 8;
    int sb = (bby & 8) | ((bby & 0x70) ^ swzr);
    *(f16x4*)(dst + it*128 + sb) = c;
  }
}

// ---------------------------------------------------------------------------
// Fused (R11 structure, best measured): phase 1 = DMA GEMM (128x192 tiles,
// A+W via global_load_lds, dbuf); phase 2 = single-jb scan dataflow tiles
// (64 rows x 64 cols). hflags>=8 (pred h), xflags>=8 (own xg).
// ---------------------------------------------------------------------------
__global__ __launch_bounds__(256, 2) void gru_fused(
    const char* __restrict__ xq, const float* __restrict__ bi,
    const float* __restrict__ bhn, const char* __restrict__ wimg,
    const float* __restrict__ h0, _Float16* __restrict__ xg,
    const u32* __restrict__ rows, const u32* __restrict__ off,
    const int* __restrict__ nlists, u32* __restrict__ hflags,
    u32* __restrict__ xflags, float* __restrict__ out)
{
  __shared__ __align__(16) char smem[81920];  // ph1: A 2x16K | W 2x24K @32768; ph2: ring 4x8K
  float* ys = out + 65536;
  const u32 n0 = off[1];
  const int tid = threadIdx.x;
  const int lane = tid & 63, wave = tid >> 6;
  const int nblk = (int)gridDim.x;

  // ================= phase 1: xg GEMM tiles (full DMA staging) =============
  int g = (int)blockIdx.x;
  while (g < NXG){
    const int tm = g >> 3, jb = g & 7;
    g += nblk;
    const char* asrc = xq + (size_t)tm * 131072;          // 128 rows x 1024 B
    const char* wsrc = wimg + ((size_t)jb * 16) * 24576;

    f32x4 acc[3][8];
    #pragma unroll
    for (int c = 0; c < 3; ++c)
      #pragma unroll
      for (int m = 0; m < 8; ++m) acc[c][m] = (f32x4){0.f,0.f,0.f,0.f};

#define DMA_A(KC, BUF) do{ \
    char* l_ = smem + (BUF)*16384 + wave*4096; \
    const char* g_ = asrc + (size_t)(wave*32 + (lane>>3))*1024 + (KC)*128 + (lane&7)*16; \
    _Pragma("unroll") for (int i_ = 0; i_ < 4; ++i_) \
      gload16(g_ + i_*8192, l_ + i_*1024); }while(0)
#define DMA_W(KC, BUF) do{ \
    char* l_ = smem + 32768 + (BUF)*24576 + wave*6144; \
    const char* g_ = wsrc + (size_t)(KC)*24576 + wave*6144 + lane*16; \
    _Pragma("unroll") for (int i_ = 0; i_ < 6; ++i_) \
      gload16(g_ + i_*1024, l_ + i_*1024); }while(0)

    DMA_A(0, 0); DMA_W(0, 0);
    __syncthreads();
    for (int kc = 0; kc < 8; ++kc){
      const int cur = kc & 1;
      if (kc < 7){ DMA_A(kc+1, cur^1); DMA_W(kc+1, cur^1); }
      const char* Ab = smem + cur*16384;
      const char* Wb = smem + 32768 + cur*24576;
      #pragma unroll
      for (int kk = 0; kk < 2; ++kk){
        const int bby = kk*64 + (lane>>4)*16;
        f16x8 af[8];
        #pragma unroll
        for (int mi = 0; mi < 8; ++mi){
          int rr = mi*16 + (lane & 15);
          af[mi] = *(const f16x8*)(Ab + rr*128 + (bby ^ ((rr & 7) << 4)));
        }
        #pragma unroll
        for (int cls = 0; cls < 3; ++cls){
          int cc = cls*64 + wave*16 + (lane & 15);
          f16x8 wf = *(const f16x8*)(Wb + cc*128 + (bby ^ ((cc & 7) << 4)));
          #pragma unroll
          for (int mi = 0; mi < 8; ++mi)
            acc[cls][mi] = __builtin_amdgcn_mfma_f32_16x16x32_f16(af[mi], wf, acc[cls][mi], 0, 0, 0);
        }
      }
      __syncthreads();
    }
#undef DMA_A
#undef DMA_W

    const int jloc = wave*16 + (lane & 15);
    const int j = jb*64 + jloc;
    const float bir = bi[j], biz = bi[512 + j], bin = bi[1024 + j], bh = bhn[j];
    #pragma unroll
    for (int mi = 0; mi < 8; ++mi){
      #pragma unroll
      for (int rg = 0; rg < 4; ++rg){
        int r = mi*16 + (lane >> 4)*4 + rg;
        u32 e = rows[tm*128 + r];
        int tt = (int)(e & 511u), bb = (int)((e >> 9) & 127u);
        float xr = acc[0][mi][rg] + bir;
        float xz = acc[1][mi][rg] + biz;
        float xn = acc[2][mi][rg] + bin;
        if ((e >> 16) == 1u){        // reset/fold row: h = (1-z)*n
          float rr = sigm(xr), zz = sigm(xz);
          float nn = tanh_fast(xn + rr*bh);
          float hv = (1.f - zz)*nn;
          ys[((size_t)(tt*128 + bb))*512 + j] = hv;
          if (tt == 511) out[(size_t)bb*512 + j] = hv;
        } else {
          u32 xi = (u32)(tm*128 + r) - n0;
          if (xi >= XGCAP) xi = 0;
          _Float16* p = xg + (size_t)xi*1536 + jb*192 + jloc;
          p[0]   = (_Float16)xr;
          p[64]  = (_Float16)xz;
          p[128] = (_Float16)xn;
        }
      }
    }
    __syncthreads();   // all stores drained before flag bumps
    if (tid < 128){
      u32 e = rows[tm*128 + tid];
      if ((e >> 16) == 1u) abump(&hflags[(e & 511u)*128u + ((e >> 9) & 127u)], 1u);
      else                 abump(&xflags[tm*128 + tid], 1u);
    }
    __syncthreads();
  }

  // ================= phase 2: scan tiles (R5 dataflow) =====================
  const int L = *nlists;
  int myNext = g - NXG;
  int gt = 0;
  for (int li = 1; li < L; ++li){
    const u32 offA = off[li];
    const int nA = (int)(off[li+1] - offA);
    const int tA = (nA + 63) >> 6;
    const int nt = tA * 8;
    while (myNext < gt + nt){
      const int tile = myNext - gt;
      myNext += nblk;
      const int tm = tile >> 3, jb = tile & 7;
      const u32 rowbase = offA + (u32)tm*64u;
      const u32 xibase = rowbase - n0;
      const int mcount = min(64, nA - tm*64);
      const char* wp = wimg + ((size_t)jb*16 + 8)*24576;
      const int jloc = wave*16 + (lane & 15);

      // wait: wave 0 polls xg readiness (own rows) + h readiness (preds)
      if (wave == 0 && lane < mcount){
        u32 e = rows[rowbase + lane];
        const bool needH = ((e >> 16) == 0u);
        u32 hidx = ((e & 511u) - 1u)*128u + ((e >> 9) & 127u);
        int guard = 0;
        for (;;){
          bool ok = apoll(&xflags[rowbase + lane]) >= 8u;
          if (ok && needH) ok = apoll(&hflags[hidx]) >= 8u;
          if (ok) break;
          __builtin_amdgcn_s_sleep(1);
          if (++guard > (1 << 20)) break;
        }
      }
      __syncthreads();

      const float* rp[4];
      #pragma unroll
      for (int i = 0; i < 4; ++i){
        u32 e = rows[rowbase + (tid>>4) + i*16];
        int tt = (int)(e & 511u), bb = (int)((e >> 9) & 127u);
        const float* base = ((e >> 16) == 0u) ? (ys + ((size_t)((tt-1)*128 + bb))*512)
                                              : (h0 + (size_t)bb*512);
        rp[i] = base + (tid & 15)*4;
      }

      // xg prefetch: 48 halves/thread, in flight across the K-pipeline
      _Float16 xgp[3][4][4];
      #pragma unroll
      for (int mi = 0; mi < 4; ++mi){
        #pragma unroll
        for (int rg = 0; rg < 4; ++rg){
          u32 xi = xibase + (u32)(mi*16 + (lane >> 4)*4 + rg);
          if (xi >= XGCAP) xi = 0;
          const _Float16* p = xg + (size_t)xi*1536 + jb*192 + jloc;
          xgp[0][mi][rg] = p[0];
          xgp[1][mi][rg] = p[64];
          xgp[2][mi][rg] = p[128];
        }
      }

      f32x4 acc[3][4];
      #pragma unroll
      for (int c = 0; c < 3; ++c)
        #pragma unroll
        for (int m = 0; m < 4; ++m) acc[c][m] = (f32x4){0.f,0.f,0.f,0.f};
      float hp[4][4];
      double s0[4][2], s1[4][2], s2[4][2];

#define ALOAD(S, CK) do{ \
    _Pragma("unroll") for (int i_ = 0; i_ < 4; ++i_){ \
      const double* p_ = (const double*)(rp[i_] + (CK)*64); \
      S[i_][0] = aload(p_); S[i_][1] = aload(p_ + 1); } }while(0)

#define AWRITE(S, CK) do{ \
    char* An_ = smem + ((CK) & 3)*8192; \
    _Pragma("unroll") for (int i_ = 0; i_ < 4; ++i_){ \
      float2 u0_ = d2f2(S[i_][0]), u1_ = d2f2(S[i_][1]); \
      int r_ = (tid>>4) + i_*16, bby_ = (tid & 15)*8; \
      int sb_ = (bby_ & 8) | ((bby_ & 0x70) ^ ((r_ & 7) << 4)); \
      f16x4 c_; c_[0]=(_Float16)u0_.x; c_[1]=(_Float16)u0_.y; \
                c_[2]=(_Float16)u1_.x; c_[3]=(_Float16)u1_.y; \
      *(f16x4*)(An_ + r_*128 + sb_) = c_; } }while(0)

#define COMPUTE(KC) do{ \
    const char* Ab_ = smem + ((KC) & 3)*8192; \
    _Pragma("unroll") for (int kk_ = 0; kk_ < 2; ++kk_){ \
      const int bby_ = kk_*64 + (lane>>4)*16; \
      f16x8 af_[4]; \
      _Pragma("unroll") for (int mi_ = 0; mi_ < 4; ++mi_){ \
        int rr_ = mi_*16 + (lane & 15); \
        af_[mi_] = *(const f16x8*)(Ab_ + rr_*128 + (bby_ ^ ((rr_ & 7) << 4))); } \
      _Pragma("unroll") for (int cl_ = 0; cl_ < 3; ++cl_){ \
        int cc_ = cl_*64 + wave*16 + (lane & 15); \
        f16x8 wf_ = *(const f16x8*)(wp + (size_t)(KC)*24576 + cc_*128 + (bby_ ^ ((cc_ & 7) << 4))); \
        _Pragma("unroll") for (int mi_ = 0; mi_ < 4; ++mi_) \
          acc[cl_][mi_] = __builtin_amdgcn_mfma_f32_16x16x32_f16(af_[mi_], wf_, acc[cl_][mi_], 0, 0, 0); } } \
    if ((KC) == jb){ \
      const int bb2_ = jloc*2; \
      _Pragma("unroll") for (int mi_ = 0; mi_ < 4; ++mi_) \
        _Pragma("unroll") for (int rg_ = 0; rg_ < 4; ++rg_){ \
          int r2_ = mi_*16 + (lane >> 4)*4 + rg_; \
          int sb2_ = (bb2_ & 0x0F) | ((bb2_ & 0x70) ^ ((r2_ & 7) << 4)); \
          hp[mi_][rg_] = (float)(*(const _Float16*)(Ab_ + r2_*128 + sb2_)); } } }while(0)

      ALOAD(s0, 0); ALOAD(s1, 1); ALOAD(s2, 2);
      AWRITE(s0, 0);
      __syncthreads();
      ALOAD(s0, 3); COMPUTE(0); AWRITE(s1, 1); __syncthreads();
      ALOAD(s1, 4); COMPUTE(1); AWRITE(s2, 2); __syncthreads();
      ALOAD(s2, 5); COMPUTE(2); AWRITE(s0, 3); __syncthreads();
      ALOAD(s0, 6); COMPUTE(3); AWRITE(s1, 4); __syncthreads();
      ALOAD(s1, 7); COMPUTE(4); AWRITE(s2, 5); __syncthreads();
                    COMPUTE(5); AWRITE(s0, 6); __syncthreads();
                    COMPUTE(6); AWRITE(s1, 7); __syncthreads();
                    COMPUTE(7);
#undef ALOAD
#undef AWRITE
#undef COMPUTE

      // epilogue: gates + h_new -> ys (agent stores) + out for t=511
      const int j = jb*64 + jloc;
      const float bh = bhn[j];
      #pragma unroll
      for (int mi = 0; mi < 4; ++mi){
        #pragma unroll
        for (int rg = 0; rg < 4; ++rg){
          int r = mi*16 + (lane >> 4)*4 + rg;
          if (r < mcount){
            u32 e = rows[rowbase + r];
            int tt = (int)(e & 511u), bb = (int)((e >> 9) & 127u);
            float rr = sigm((float)xgp[0][mi][rg] + acc[0][mi][rg]);
            float zz = sigm((float)xgp[1][mi][rg] + acc[1][mi][rg]);
            float nn = tanh_fast((float)xgp[2][mi][rg] + rr*(acc[2][mi][rg] + bh));
            float hv = (1.f - zz)*nn + zz*hp[mi][rg];
            astore(&ys[((size_t)(tt*128 + bb))*512 + j], hv);
            if (tt == 511) out[(size_t)bb*512 + j] = hv;
          }
        }
      }
      __syncthreads();   // vmcnt(0) drained -> ys stores at coherence point
      if (tid < mcount){
        u32 e = rows[rowbase + tid];
        abump(&hflags[(e & 511u)*128u + ((e >> 9) & 127u)], 1u);
      }
    }
    gt += nt;
  }
}

// ---------------------------------------------------------------------------
extern "C" void kernel_launch(void* const* d_in, const int* in_sizes, int n_in,
                              void* d_out, int out_size, void* d_ws, size_t ws_size,
                              hipStream_t stream)
{
  const float* x  = (const float*)d_in[0];
  const void*  resets = d_in[1];
  const float* h0 = (const float*)d_in[2];
  const float* Wi = (const float*)d_in[3];
  const float* bi = (const float*)d_in[4];
  const float* Wh = (const float*)d_in[5];
  const float* bhn= (const float*)d_in[6];
  float* out = (float*)d_out;

  char* ws = (char*)d_ws;
  u32* off    = (u32*)ws;                       // 521 u32
  int* nlists = (int*)(ws + 4096);
  u32* rows   = (u32*)(ws + 8192);              // 65600 u32
  u32* hflags = (u32*)(ws + 294912);            // 65536 u32
  u32* xflags = (u32*)(ws + 557056);            // 65536 u32 (contiguous after hflags)
  char* wimg  = ws + 819200;                    // 3.07 MB
  char* xq    = ws + 4194304;                   // 67.1 MB
  _Float16* xg = (_Float16*)(ws + 71303168);    // XGCAP*1536 fp16 = 105.4 MB

  prep_lists<<<dim3(1), dim3(512), 0, stream>>>(resets, h0, rows, off, nlists);
  prep_w<<<dim3(384), dim3(256), 0, stream>>>(Wi, Wh, wimg, hflags);
  prep_x<<<dim3(4096), dim3(256), 0, stream>>>(x, rows, xq);

  int perCU = 0;
  (void)hipOccupancyMaxActiveBlocksPerMultiprocessor(&perCU, gru_fused, 256, 0);
  if (perCU < 1) perCU = 1;
  int grid = perCU * 256;
  if (grid > 1024) grid = 1024;

  void* args[] = {(void*)&xq, (void*)&bi, (void*)&bhn, (void*)&wimg,
                  (void*)&h0, (void*)&xg, (void*)&rows, (void*)&off,
                  (void*)&nlists, (void*)&hflags, (void*)&xflags, (void*)&out};
  hipLaunchCooperativeKernel(gru_fused, dim3(grid), dim3(256), args, 0, stream);

  (void)in_sizes; (void)n_in; (void)out_size; (void)ws_size;
}